// Round 10
// baseline (385.513 us; speedup 1.0000x reference)
//
#include <hip/hip_runtime.h>
#include <math.h>

#define BSZ 64
#define NPT 16384
#define SEG 16
#define NFPS 256
#define RCAP 2048        // per-problem compacted-region capacity (count ~1024±31)
#define NLANES 64

typedef __attribute__((ext_vector_type(2))) float f32x2;

// Packed f32 ops (VOP3P) — per-element IEEE rn, bit-exact vs scalar.
__device__ __forceinline__ f32x2 pk_add(f32x2 a, f32x2 b) {
    f32x2 d;
    asm("v_pk_add_f32 %0, %1, %2" : "=v"(d) : "v"(a), "v"(b));
    return d;
}
__device__ __forceinline__ f32x2 pk_mul(f32x2 a, f32x2 b) {
    f32x2 d;
    asm("v_pk_mul_f32 %0, %1, %2" : "=v"(d) : "v"(a), "v"(b));
    return d;
}

// One step of wave64 f32 max-reduce-to-lane63; bound_ctrl=1 shifts in 0.0f,
// the identity here (per-lane best >= 0: slot 0 of every lane is valid).
template <int CTRL>
__device__ __forceinline__ float dpp_max_f32(float v) {
    const int o = __builtin_amdgcn_update_dpp(0, __float_as_int(v), CTRL, 0xf, 0xf, true);
    return fmaxf(v, __int_as_float(o));
}

// Dual-problem FPS: two independent pipelines (A: region [0,RCAP), B: [RCAP,2*RCAP))
// in one wave; compiler interleaves the streams to fill dependency bubbles.
template <int P>
__device__ __forceinline__ void fps2_dual(const float4* __restrict__ pts,
                                          float* __restrict__ out,
                                          size_t gpA, size_t gpB,
                                          int cA, int cB, bool vA, bool vB, int lane) {
    f32x2 xA[P], yA[P], zA[P], xB[P], yB[P], zB[P];
    float mdA[2 * P], mdB[2 * P];
    #pragma unroll
    for (int p = 0; p < P; ++p) {
        const int i0 = (2 * p) * NLANES + lane;
        const int i1 = i0 + NLANES;
        const bool a0 = (i0 < cA), a1 = (i1 < cA);
        const bool b0 = (i0 < cB), b1 = (i1 < cB);
        const float4 qa0 = pts[a0 ? i0 : 0];
        const float4 qa1 = pts[a1 ? i1 : 0];
        const float4 qb0 = pts[RCAP + (b0 ? i0 : 0)];
        const float4 qb1 = pts[RCAP + (b1 ? i1 : 0)];
        xA[p].x = qa0.x; xA[p].y = qa1.x; yA[p].x = qa0.y; yA[p].y = qa1.y;
        zA[p].x = qa0.z; zA[p].y = qa1.z;
        xB[p].x = qb0.x; xB[p].y = qb1.x; yB[p].x = qb0.y; yB[p].y = qb1.y;
        zB[p].x = qb0.z; zB[p].y = qb1.z;
        mdA[2 * p] = a0 ? INFINITY : -INFINITY;
        mdA[2 * p + 1] = a1 ? INFINITY : -INFINITY;
        mdB[2 * p] = b0 ? INFINITY : -INFINITY;
        mdB[2 * p + 1] = b1 ? INFINITY : -INFINITY;
    }

    float4 ca = pts[0];      // first masked point of A
    float4 cb = pts[RCAP];   // first masked point of B
    for (int t = 0; t < NFPS; ++t) {
        if (vA && lane < 3)
            out[gpA + (size_t)t * 3 + lane] = (lane == 0) ? ca.x : ((lane == 1) ? ca.y : ca.z);
        if (vB && lane >= 32 && lane < 35)
            out[gpB + (size_t)t * 3 + (lane - 32)] =
                (lane == 32) ? cb.x : ((lane == 33) ? cb.y : cb.z);

        f32x2 nax; nax.x = -ca.x; nax.y = -ca.x;
        f32x2 nay; nay.x = -ca.y; nay.y = -ca.y;
        f32x2 naz; naz.x = -ca.z; naz.y = -ca.z;
        f32x2 nbx; nbx.x = -cb.x; nbx.y = -cb.x;
        f32x2 nby; nby.x = -cb.y; nby.y = -cb.y;
        f32x2 nbz; nbz.x = -cb.z; nbz.y = -cb.z;

        // Distance cores (bit-exact (dx*dx+dy*dy)+dz*dz, rn, no FMA), 4 acc
        // chains each; A and B fully independent -> scheduler interleaves.
        float a0 = -INFINITY, a1 = -INFINITY, a2 = -INFINITY, a3 = -INFINITY;
        float b0 = -INFINITY, b1 = -INFINITY, b2 = -INFINITY, b3 = -INFINITY;
        #pragma unroll
        for (int p = 0; p < P; ++p) {
            const f32x2 dxa = pk_add(xA[p], nax);
            const f32x2 dya = pk_add(yA[p], nay);
            const f32x2 dza = pk_add(zA[p], naz);
            const f32x2 da = pk_add(pk_add(pk_mul(dxa, dxa), pk_mul(dya, dya)), pk_mul(dza, dza));
            const float ma0 = fminf(mdA[2 * p], da.x);
            const float ma1 = fminf(mdA[2 * p + 1], da.y);
            mdA[2 * p] = ma0; mdA[2 * p + 1] = ma1;
            if (p & 1) { a2 = fmaxf(a2, ma0); a3 = fmaxf(a3, ma1); }
            else       { a0 = fmaxf(a0, ma0); a1 = fmaxf(a1, ma1); }

            const f32x2 dxb = pk_add(xB[p], nbx);
            const f32x2 dyb = pk_add(yB[p], nby);
            const f32x2 dzb = pk_add(zB[p], nbz);
            const f32x2 db = pk_add(pk_add(pk_mul(dxb, dxb), pk_mul(dyb, dyb)), pk_mul(dzb, dzb));
            const float mb0 = fminf(mdB[2 * p], db.x);
            const float mb1 = fminf(mdB[2 * p + 1], db.y);
            mdB[2 * p] = mb0; mdB[2 * p + 1] = mb1;
            if (p & 1) { b2 = fmaxf(b2, mb0); b3 = fmaxf(b3, mb1); }
            else       { b0 = fmaxf(b0, mb0); b1 = fmaxf(b1, mb1); }
        }
        float bestA = fmaxf(fmaxf(a0, a1), fmaxf(a2, a3));
        float bestB = fmaxf(fmaxf(b0, b1), fmaxf(b2, b3));

        // wave64 value maxes (fmax/fmin return operand bits exactly)
        bestA = dpp_max_f32<0x111>(bestA); bestB = dpp_max_f32<0x111>(bestB);
        bestA = dpp_max_f32<0x112>(bestA); bestB = dpp_max_f32<0x112>(bestB);
        bestA = dpp_max_f32<0x114>(bestA); bestB = dpp_max_f32<0x114>(bestB);
        bestA = dpp_max_f32<0x118>(bestA); bestB = dpp_max_f32<0x118>(bestB);
        bestA = dpp_max_f32<0x142>(bestA); bestB = dpp_max_f32<0x142>(bestB);
        bestA = dpp_max_f32<0x143>(bestA); bestB = dpp_max_f32<0x143>(bestB);
        const float wvA = __int_as_float(__builtin_amdgcn_readlane(__float_as_int(bestA), 63));
        const float wvB = __int_as_float(__builtin_amdgcn_readlane(__float_as_int(bestB), 63));

        // Rescan for winners: 4 parallel descending strided chains -> lowest
        // matching slot per lane; lowest matching lane via ballot.
        int ac0 = 0x7fff, ac1 = 0x7fff, ac2 = 0x7fff, ac3 = 0x7fff;
        int bc0 = 0x7fff, bc1 = 0x7fff, bc2 = 0x7fff, bc3 = 0x7fff;
        #pragma unroll
        for (int sl = 2 * P - 1; sl >= 0; --sl) {
            const bool ha = (mdA[sl] == wvA);
            const bool hb = (mdB[sl] == wvB);
            switch (sl & 3) {
                case 0: ac0 = ha ? sl : ac0; bc0 = hb ? sl : bc0; break;
                case 1: ac1 = ha ? sl : ac1; bc1 = hb ? sl : bc1; break;
                case 2: ac2 = ha ? sl : ac2; bc2 = hb ? sl : bc2; break;
                case 3: ac3 = ha ? sl : ac3; bc3 = hb ? sl : bc3; break;
            }
        }
        const int msA = min(min(ac0, ac1), min(ac2, ac3));
        const int msB = min(min(bc0, bc1), min(bc2, bc3));

        const unsigned long long bmA = __ballot(msA != 0x7fff);
        const unsigned long long bmB = __ballot(msB != 0x7fff);
        const int wlA = __builtin_amdgcn_readfirstlane(__ffsll((long long)bmA) - 1);
        const int wlB = __builtin_amdgcn_readfirstlane(__ffsll((long long)bmB) - 1);
        const int wslA = min(__builtin_amdgcn_readlane(msA, wlA & 63), 2 * P - 1);
        const int wslB = min(__builtin_amdgcn_readlane(msB, wlB & 63), 2 * P - 1);
        ca = pts[wslA * NLANES + (wlA & 63)];          // uniform ds_read_b128
        cb = pts[RCAP + wslB * NLANES + (wlB & 63)];
    }
}

__global__ __launch_bounds__(NLANES, 1) void fps_part_kernel(const float* __restrict__ x,
                                                             float* __restrict__ out) {
    // 512 blocks: one wave handles segments {2*sp, 2*sp+1} of batch b.
    // XCD swizzle: the 8 pair-blocks of one batch share blockIdx%8 -> same XCD L2.
    const int blk = blockIdx.x;
    const int xcd = blk & 7;
    const int grp = blk >> 3;                 // 0..63
    const int b = (xcd << 3) | (grp >> 3);    // 8 batches per XCD
    const int sp = grp & 7;                   // segment pair
    const int s0 = 2 * sp, s1 = 2 * sp + 1;
    const int probA = b * SEG + s0;
    const int probB = b * SEG + s1;
    const int lane = threadIdx.x;             // single wave

    __shared__ float4 pts[2 * RCAP];          // [A region | B region]

    // ---- Phase 1: one pass over the batch, compacting BOTH segments ----
    const float4* x4 = (const float4*)x + (size_t)b * NPT;
    const float fsA = (float)s0, fsB = (float)s1;
    int tA = 0, tB = 0;

    for (int mc = 0; mc < 32; ++mc) {
        float4 p[8];
        #pragma unroll
        for (int j = 0; j < 8; ++j)
            p[j] = x4[(mc * 8 + j) * NLANES + lane];
        #pragma unroll
        for (int j = 0; j < 8; ++j) {
            const bool prA = (p[j].w == fsA);
            const bool prB = (p[j].w == fsB);
            const unsigned long long mA = __ballot(prA);
            const unsigned long long mB = __ballot(prB);
            const int posA = tA + __builtin_amdgcn_mbcnt_hi((unsigned)(mA >> 32),
                                  __builtin_amdgcn_mbcnt_lo((unsigned)mA, 0));
            const int posB = tB + __builtin_amdgcn_mbcnt_hi((unsigned)(mB >> 32),
                                  __builtin_amdgcn_mbcnt_lo((unsigned)mB, 0));
            if (prA && posA < RCAP) pts[posA] = p[j];
            if (prB && posB < RCAP) pts[RCAP + posB] = p[j];
            tA += __popcll(mA);
            tB += __popcll(mB);
        }
    }
    __syncthreads();  // single wave: cheap; orders ds_writes before ds_reads

    const int cA = (tA < RCAP) ? tA : RCAP;
    const int cB = (tB < RCAP) ? tB : RCAP;
    const bool vA = (cA >= NFPS), vB = (cB >= NFPS);
    const size_t gpA = (size_t)probA * NFPS * 3;
    const size_t gpB = (size_t)probB * NFPS * 3;
    const size_t maskbase = (size_t)BSZ * SEG * NFPS * 3;

    if (lane == 0) {
        out[maskbase + probA] = vA ? 1.0f : 0.0f;
        out[maskbase + probB] = vB ? 1.0f : 0.0f;
    }
    if (!vA) for (int i = lane; i < NFPS * 3; i += NLANES) out[gpA + i] = 0.0f;
    if (!vB) for (int i = lane; i < NFPS * 3; i += NLANES) out[gpB + i] = 0.0f;
    if (!vA && !vB) return;

    // ---- Phase 2: compile-time pair count (shared by A and B; pads are -inf) ----
    const int cmx = (cA > cB) ? cA : cB;
    const int pmax = (__builtin_amdgcn_readfirstlane(cmx) + 127) >> 7;

    if (pmax <= 8)       fps2_dual<8>(pts, out, gpA, gpB, cA, cB, vA, vB, lane);
    else if (pmax == 9)  fps2_dual<9>(pts, out, gpA, gpB, cA, cB, vA, vB, lane);
    else if (pmax == 10) fps2_dual<10>(pts, out, gpA, gpB, cA, cB, vA, vB, lane);
    else                 fps2_dual<16>(pts, out, gpA, gpB, cA, cB, vA, vB, lane);
}

extern "C" void kernel_launch(void* const* d_in, const int* in_sizes, int n_in,
                              void* d_out, int out_size, void* d_ws, size_t ws_size,
                              hipStream_t stream) {
    const float* x = (const float*)d_in[0];
    float* out = (float*)d_out;
    fps_part_kernel<<<BSZ * SEG / 2, NLANES, 0, stream>>>(x, out);
}

// Round 12
// 245.135 us; speedup vs baseline: 1.5727x; 1.5727x over previous
//
#include <hip/hip_runtime.h>
#include <math.h>

#define BSZ 64
#define NPT 16384
#define SEG 16
#define NFPS 256
#define MAXPTS 2048
#define NLANES 64

typedef __attribute__((ext_vector_type(2))) float f32x2;

// Packed f32 ops (VOP3P) — per-element IEEE rn, bit-exact vs scalar.
__device__ __forceinline__ f32x2 pk_add(f32x2 a, f32x2 b) {
    f32x2 d;
    asm("v_pk_add_f32 %0, %1, %2" : "=v"(d) : "v"(a), "v"(b));
    return d;
}
__device__ __forceinline__ f32x2 pk_mul(f32x2 a, f32x2 b) {
    f32x2 d;
    asm("v_pk_mul_f32 %0, %1, %2" : "=v"(d) : "v"(a), "v"(b));
    return d;
}

// u64 max with DPP-shifted partner (reduce-to-lane63). bound_ctrl=1 shifts in
// 0 == identity (keys >= 0: hi word is positive-float bits). Proven in R3.
template <int CTRL>
__device__ __forceinline__ unsigned long long dpp_max_u64(unsigned long long k) {
    const int lo = __builtin_amdgcn_update_dpp(0, (int)(unsigned)k, CTRL, 0xf, 0xf, true);
    const int hi = __builtin_amdgcn_update_dpp(0, (int)(unsigned)(k >> 32), CTRL, 0xf, 0xf, true);
    const unsigned long long ok = ((unsigned long long)(unsigned)hi << 32) | (unsigned)lo;
    return ok > k ? ok : k;
}

// Phase 2 with compile-time pair count P (covers count <= 128*P; pads -inf).
template <int P>
__device__ __forceinline__ void fps_phase2(const float4* __restrict__ pts,
                                           float* __restrict__ out,
                                           size_t gp_base, int count, int lane) {
    f32x2 xp[P], yp[P], zp[P];
    float md[2 * P];
    #pragma unroll
    for (int p = 0; p < P; ++p) {
        const int i0 = (2 * p) * NLANES + lane;
        const int i1 = i0 + NLANES;
        const bool v0 = (i0 < count), v1 = (i1 < count);
        const float4 q0 = pts[v0 ? i0 : 0];
        const float4 q1 = pts[v1 ? i1 : 0];
        xp[p].x = q0.x; xp[p].y = q1.x;
        yp[p].x = q0.y; yp[p].y = q1.y;
        zp[p].x = q0.z; zp[p].y = q1.z;
        md[2 * p]     = v0 ? INFINITY : -INFINITY;
        md[2 * p + 1] = v1 ? INFINITY : -INFINITY;
    }

    float4 c = pts[0];          // first masked point == argmax(mask)
    float scx[4], scy[4], scz[4];  // selected-point register banks (t = c4*64+lane)

    #pragma unroll
    for (int c4 = 0; c4 < 4; ++c4) {
        for (int tt = 0; tt < 64; ++tt) {
            // save this iteration's cur_pt into bank c4 on lane tt (no global store)
            const bool mine = (lane == tt);
            scx[c4] = mine ? c.x : scx[c4];
            scy[c4] = mine ? c.y : scy[c4];
            scz[c4] = mine ? c.z : scz[c4];

            f32x2 ncx; ncx.x = -c.x; ncx.y = -c.x;
            f32x2 ncy; ncy.x = -c.y; ncy.y = -c.y;
            f32x2 ncz; ncz.x = -c.z; ncz.y = -c.z;

            // 4 (value,slot) tracking chains. Slots 0..3 are always valid
            // (count>=256) -> every chain ends finite non-negative; strict >
            // keeps the lowest slot within each chain.
            float bv0 = -INFINITY, bv1 = -INFINITY, bv2 = -INFINITY, bv3 = -INFINITY;
            int bs0 = 0, bs1 = 0, bs2 = 0, bs3 = 0;
            #pragma unroll
            for (int p = 0; p < P; ++p) {
                // Bit-exact: (dx*dx + dy*dy) + dz*dz, rn, no FMA; a-b == a+(-b).
                const f32x2 dx = pk_add(xp[p], ncx);
                const f32x2 dy = pk_add(yp[p], ncy);
                const f32x2 dz = pk_add(zp[p], ncz);
                const f32x2 d = pk_add(pk_add(pk_mul(dx, dx), pk_mul(dy, dy)),
                                       pk_mul(dz, dz));
                const float m0 = fminf(md[2 * p], d.x);
                const float m1 = fminf(md[2 * p + 1], d.y);
                md[2 * p] = m0;
                md[2 * p + 1] = m1;
                if (p & 1) {
                    if (m0 > bv2) { bv2 = m0; bs2 = 2 * p; }
                    if (m1 > bv3) { bv3 = m1; bs3 = 2 * p + 1; }
                } else {
                    if (m0 > bv0) { bv0 = m0; bs0 = 2 * p; }
                    if (m1 > bv1) { bv1 = m1; bs1 = 2 * p + 1; }
                }
            }

            // Pack u64 keys: (value_bits << 32) | ~(slot*64+lane).
            // u64 max == (max value, min compacted idx) == np.argmax first-max.
            const unsigned lo0 = ~(unsigned)((bs0 << 6) | lane);
            const unsigned lo1 = ~(unsigned)((bs1 << 6) | lane);
            const unsigned lo2 = ~(unsigned)((bs2 << 6) | lane);
            const unsigned lo3 = ~(unsigned)((bs3 << 6) | lane);
            unsigned long long k0 = ((unsigned long long)__float_as_uint(bv0) << 32) | lo0;
            const unsigned long long k1 = ((unsigned long long)__float_as_uint(bv1) << 32) | lo1;
            unsigned long long k2 = ((unsigned long long)__float_as_uint(bv2) << 32) | lo2;
            const unsigned long long k3 = ((unsigned long long)__float_as_uint(bv3) << 32) | lo3;
            if (k1 > k0) k0 = k1;
            if (k3 > k2) k2 = k3;
            unsigned long long key = (k2 > k0) ? k2 : k0;

            // wave64 u64 max reduce to lane 63 (DPP; lo/hi movs independent)
            key = dpp_max_u64<0x111>(key);  // row_shr:1
            key = dpp_max_u64<0x112>(key);  // row_shr:2
            key = dpp_max_u64<0x114>(key);  // row_shr:4
            key = dpp_max_u64<0x118>(key);  // row_shr:8
            key = dpp_max_u64<0x142>(key);  // row_bcast:15
            key = dpp_max_u64<0x143>(key);  // row_bcast:31

            // single scalar round-trip: one readlane -> uniform idx -> LDS bcast
            const unsigned keylo =
                (unsigned)__builtin_amdgcn_readlane((int)(unsigned)key, 63);
            const int idx = (int)(~keylo);
            c = pts[idx];               // uniform-addr ds_read_b128 broadcast
        }
    }

    // batched output: 12 stores per lane, once
    #pragma unroll
    for (int c4 = 0; c4 < 4; ++c4) {
        const size_t o = gp_base + (size_t)(c4 * 64 + lane) * 3;
        out[o + 0] = scx[c4];
        out[o + 1] = scy[c4];
        out[o + 2] = scz[c4];
    }
}

__global__ __launch_bounds__(NLANES, 1) void fps_part_kernel(const float* __restrict__ x,
                                                             float* __restrict__ out) {
    // XCD swizzle: all 16 segment-blocks of one batch share blockIdx%8 -> same
    // XCD L2 caches that batch's 256KB slice once (8 batches/XCD = 2MB < 4MB L2).
    const int blk = blockIdx.x;
    const int xcd = blk & 7;
    const int grp = blk >> 3;            // 0..127
    const int b = (xcd << 3) | (grp >> 4);
    const int s = grp & 15;
    const int prob = b * SEG + s;        // logical problem id (output slot)
    const int lane = threadIdx.x;        // single wave

    __shared__ float4 pts[MAXPTS];

    // ---------------- Phase 1: stable compaction (wave-coherent, no barriers) ----------------
    const float4* x4 = (const float4*)x + (size_t)b * NPT;
    const float fs = (float)s;
    const unsigned long long lanemask = (1ull << lane) - 1ull;
    int total = 0;

    for (int mc = 0; mc < 32; ++mc) {
        float4 p[8];
        #pragma unroll
        for (int j = 0; j < 8; ++j)
            p[j] = x4[(mc * 8 + j) * NLANES + lane];
        #pragma unroll
        for (int j = 0; j < 8; ++j) {
            const bool pred = (p[j].w == fs);
            const unsigned long long m = __ballot(pred);
            const int pos = total + __popcll(m & lanemask);
            if (pred && pos < MAXPTS) pts[pos] = p[j];
            total += __popcll(m);   // uniform -> SALU
        }
    }
    __syncthreads();  // single wave: cheap; orders ds_writes before ds_reads

    const int count = (total < MAXPTS) ? total : MAXPTS;
    const size_t gp_base = (size_t)prob * NFPS * 3;
    const size_t mask_off = (size_t)BSZ * SEG * NFPS * 3 + (size_t)prob;

    if (count < NFPS) {
        for (int i = lane; i < NFPS * 3; i += NLANES) out[gp_base + i] = 0.0f;
        if (lane == 0) out[mask_off] = 0.0f;
        return;
    }
    if (lane == 0) out[mask_off] = 1.0f;

    // ---------------- Phase 2: compile-time-specialized pair count ----------------
    const int cnt_s = __builtin_amdgcn_readfirstlane(count);
    const int pmax = (cnt_s + 127) >> 7;   // ceil(count/128); ~8-9 for count~1024

    if (pmax <= 8)       fps_phase2<8>(pts, out, gp_base, count, lane);
    else if (pmax == 9)  fps_phase2<9>(pts, out, gp_base, count, lane);
    else                 fps_phase2<16>(pts, out, gp_base, count, lane);
}

extern "C" void kernel_launch(void* const* d_in, const int* in_sizes, int n_in,
                              void* d_out, int out_size, void* d_ws, size_t ws_size,
                              hipStream_t stream) {
    const float* x = (const float*)d_in[0];
    float* out = (float*)d_out;
    fps_part_kernel<<<BSZ * SEG, NLANES, 0, stream>>>(x, out);
}